// Round 12
// baseline (60.433 us; speedup 1.0000x reference)
//
#include <hip/hip_runtime.h>
#include <stdint.h>

#define T_DIM 4096
#define S_DIM 16384          // 4 batches x 4096
#define EPSF 1e-12f

typedef __attribute__((ext_vector_type(8))) short   short8v;
typedef __attribute__((ext_vector_type(4))) float   float4v;
typedef __attribute__((ext_vector_type(4))) uint32_t uint4v;

__device__ __forceinline__ unsigned short f2bf_rne(float f) {
    uint32_t u = __builtin_bit_cast(uint32_t, f);
    return (unsigned short)((u + 0x7fffu + ((u >> 16) & 1u)) >> 16);
}
__device__ __forceinline__ uint32_t cvtpk(float lo, float hi) {
    uint32_t r;
    asm("v_cvt_pk_bf16_f32 %0, %1, %2" : "=v"(r) : "v"(lo), "v"(hi));
    return r;
}

#define GLOAD_LDS16(gsrc, ldst)                                                     \
    __builtin_amdgcn_global_load_lds(                                               \
        (const __attribute__((address_space(1))) void*)(gsrc),                      \
        (__attribute__((address_space(3))) void*)(ldst), 16, 0, 0)

// ---------------------------------------------------------------------------
// K0: conv_w [k=4096][n=64] f32 -> bf16 fragment stream wfrag[cc][nt][h][ln]x16B
//     granule (cc,nt,h,ln) holds W[cc*64 + h*32 + (ln>>4)*8 + j][nt*16+(ln&15)]
// ---------------------------------------------------------------------------
__global__ __launch_bounds__(256) void k_convert(const float* __restrict__ conv_w,
                                                 unsigned short* __restrict__ wfrag) {
    __shared__ unsigned short lb[64][65];
    int tid = threadIdx.x;
    int cc  = blockIdx.x;                       // 0..63
    for (int i = tid; i < 4096; i += 256) {     // coalesced read of 16KB slab
        lb[i >> 6][i & 63] = f2bf_rne(conv_w[((size_t)cc << 12) + i]);
    }
    __syncthreads();
    for (int gi = tid; gi < 512; gi += 256) {
        int nt = gi >> 7, h = (gi >> 6) & 1, ln = gi & 63;
        int n  = (nt << 4) + (ln & 15);
        int kb = (h << 5) + ((ln >> 4) << 3);
        uint4v u;
        #pragma unroll
        for (int q = 0; q < 4; ++q)
            u[q] = (uint32_t)lb[kb + 2 * q][n] | ((uint32_t)lb[kb + 2 * q + 1][n] << 16);
        *(uint4v*)(wfrag + ((size_t)cc << 12) + (gi << 3)) = u;
    }
}

// ---------------------------------------------------------------------------
// K1: dots + norm partials.  Block = 64 positions (lane = position).
// ---------------------------------------------------------------------------
__global__ __launch_bounds__(256) void k_dotsP(const float* __restrict__ x,
                                               const float* __restrict__ w,
                                               float* __restrict__ P) {
    __shared__ float xt[78 * 65];       // pitch 65, rows s0..s0+77
    __shared__ float pd[4][64][17];
    __shared__ float dsq[64][17];
    int tid = threadIdx.x, lane = tid & 63, wv = tid >> 6;
    int s0 = blockIdx.x << 6;
    int bt0 = s0 & (T_DIM - 1);
    for (int i = tid; i < 78 * 16; i += 256) {
        int r = i >> 4, c4 = (i & 15) << 2;
        float4v v = {0.f, 0.f, 0.f, 0.f};
        if (bt0 + r < T_DIM) v = *(const float4v*)(x + (((size_t)(s0 + r)) << 6) + c4);
        #pragma unroll
        for (int q = 0; q < 4; ++q) xt[r * 65 + c4 + q] = v[q];
    }
    __syncthreads();
    float acc[15];
    #pragma unroll
    for (int j = 0; j < 15; ++j) acc[j] = 0.f;
    int c0 = wv << 4;
    for (int c = c0; c < c0 + 16; ++c) {
        const float* base = &xt[lane * 65 + c];
        float xl = base[0];
        #pragma unroll
        for (int j = 0; j < 15; ++j) acc[j] += xl * base[j * 65];
    }
    #pragma unroll
    for (int j = 0; j < 15; ++j) pd[wv][lane][j] = acc[j];
    __syncthreads();
    for (int i = tid; i < 960; i += 256) {      // i = j*64 + s
        int s = i & 63, j = i >> 6;
        float d = pd[0][s][j] + pd[1][s][j] + pd[2][s][j] + pd[3][s][j];
        dsq[s][j] = d * d;
    }
    __syncthreads();
    for (int i = tid; i < 960; i += 256) {      // i = l*64 + s  (coalesced P writes)
        int s = i & 63, l = i >> 6;
        float sum = w[l] * dsq[s][0];
        for (int j = 1; j <= 14 - l; ++j) sum += 2.f * w[l + j] * dsq[s][j];
        P[(size_t)l * S_DIM + s0 + s] = sum;
    }
}

// ---------------------------------------------------------------------------
// K2: rsq[s] = rsqrt(max(sum_l w_l * P[l][s+l-7], eps))
// ---------------------------------------------------------------------------
__global__ __launch_bounds__(256) void k_rsq(const float* __restrict__ P,
                                             const float* __restrict__ w,
                                             float* __restrict__ rsq) {
    int s = blockIdx.x * 256 + threadIdx.x;
    int t = s & (T_DIM - 1);
    float sum = 0.f;
    #pragma unroll
    for (int l = 0; l < 15; ++l) {
        int tp = t + l - 7;
        if (0 <= tp && tp < T_DIM) sum += w[l] * P[(size_t)l * S_DIM + s + l - 7];
    }
    rsq[s] = rsqrtf(fmaxf(sum, EPSF));
}

// ---------------------------------------------------------------------------
// K3: GEMM g_part[split][s][n] (M=16384, K=4096, N=64), F on the fly.
// R8 geometry (BM=64, 256 thr, split=4, 1024 blocks = 4 blocks/CU — the
// proven-required occupancy) with a 2x2 wave->work remap: wave w covers
// rowgroups (w&1)*2..+1 and n-quadrants (w>>1)*2..+1. Each wave reads only
// 4 granules/c (was 8, 4x redundant across waves) for the same 8 MFMAs ->
// LDS reads halve; MFMA becomes the binding pipe. VGPR ~100 (fits 4/SIMD).
// Per-output MFMA order unchanged -> absmax canary 4.882812e-4.
// Stage/barrier = R8-proven T3-minimal 2-phase. unroll 2 only (R5).
// ---------------------------------------------------------------------------
__global__ __launch_bounds__(256, 4) void k_gemm(const float* __restrict__ x,
                                                 const unsigned short* __restrict__ wfrag,
                                                 float* __restrict__ g) {
    __shared__ alignas(16) unsigned short wbuf[2][4096];   // 2 x 8KB chunk
    int tid = threadIdx.x, lane = tid & 63, wv = tid >> 6;
    int split = blockIdx.x & 3;
    int m0 = (blockIdx.x >> 2) << 6;            // 64 rows per block
    int c0 = split << 4;                        // 16 c-columns per split

    int arow   = lane & 15;
    int kgrp   = (lane >> 4) << 3;
    int rgbase = (wv & 1) << 5;                 // row offset of this wave's rg pair
    int ntb    = (wv >> 1) << 1;                // first n-quadrant of this wave's pair

    const float* xr0 = x + (((size_t)(m0 + rgbase + arow)) << 6);        // rg A
    const float* xr1 = x + (((size_t)(m0 + rgbase + 16 + arow)) << 6);   // rg B
    // A-operand d-half registers (fixed across the K loop), per row-group
    float4v p00a = *(const float4v*)(xr0 + kgrp);
    float4v p01a = *(const float4v*)(xr0 + kgrp + 4);
    float4v p10a = *(const float4v*)(xr0 + 32 + kgrp);
    float4v p11a = *(const float4v*)(xr0 + 36 + kgrp);
    float4v p00b = *(const float4v*)(xr1 + kgrp);
    float4v p01b = *(const float4v*)(xr1 + kgrp + 4);
    float4v p10b = *(const float4v*)(xr1 + 32 + kgrp);
    float4v p11b = *(const float4v*)(xr1 + 36 + kgrp);

    const char* wsb = (const char*)wfrag;
#define STAGE_CHUNK(bi, c) do {                                                   \
        GLOAD_LDS16(wsb + ((size_t)(c) << 13) + (tid << 4),                       \
                    (char*)&wbuf[bi][0] + (wv << 10));                            \
        GLOAD_LDS16(wsb + ((size_t)(c) << 13) + 4096 + (tid << 4),                \
                    (char*)&wbuf[bi][0] + 4096 + (wv << 10));                     \
    } while (0)

    float4v acc[2][2];                          // [rg][nt-local]
    #pragma unroll
    for (int rg = 0; rg < 2; ++rg)
        #pragma unroll
        for (int q = 0; q < 2; ++q)
            #pragma unroll
            for (int j = 0; j < 4; ++j) acc[rg][q][j] = 0.f;

    const short8v* fb0 = (const short8v*)&wbuf[0][0];
    const short8v* fb1 = (const short8v*)&wbuf[1][0];

    STAGE_CHUNK(0, c0);
    __syncthreads();                    // chunk 0 resident

    #pragma unroll 2
    for (int ci = 0; ci < 16; ++ci) {
        if (ci < 15) STAGE_CHUNK((ci + 1) & 1, c0 + ci + 1);   // overlaps compute

        const short8v* fb = (ci & 1) ? fb1 : fb0;
        // this wave's 4 granules: 2 quadrants x 2 halves
        short8v b00 = fb[(ntb << 7) + lane];
        short8v b01 = fb[(ntb << 7) + 64 + lane];
        short8v b10 = fb[((ntb + 1) << 7) + lane];
        short8v b11 = fb[((ntb + 1) << 7) + 64 + lane];

        // ---- row-group A ----
        {
            float xc = xr0[c0 + ci];
            union { uint32_t u[4]; short8v s; } a0, a1;
            float4v q0 = p00a * xc, q1 = p01a * xc, q2 = p10a * xc, q3 = p11a * xc;
            a0.u[0] = cvtpk(q0[0], q0[1]); a0.u[1] = cvtpk(q0[2], q0[3]);
            a0.u[2] = cvtpk(q1[0], q1[1]); a0.u[3] = cvtpk(q1[2], q1[3]);
            a1.u[0] = cvtpk(q2[0], q2[1]); a1.u[1] = cvtpk(q2[2], q2[3]);
            a1.u[2] = cvtpk(q3[0], q3[1]); a1.u[3] = cvtpk(q3[2], q3[3]);
            acc[0][0] = __builtin_amdgcn_mfma_f32_16x16x32_bf16(a0.s, b00, acc[0][0], 0, 0, 0);
            acc[0][0] = __builtin_amdgcn_mfma_f32_16x16x32_bf16(a1.s, b01, acc[0][0], 0, 0, 0);
            acc[0][1] = __builtin_amdgcn_mfma_f32_16x16x32_bf16(a0.s, b10, acc[0][1], 0, 0, 0);
            acc[0][1] = __builtin_amdgcn_mfma_f32_16x16x32_bf16(a1.s, b11, acc[0][1], 0, 0, 0);
        }
        // ---- row-group B ----
        {
            float xc = xr1[c0 + ci];
            union { uint32_t u[4]; short8v s; } a0, a1;
            float4v q0 = p00b * xc, q1 = p01b * xc, q2 = p10b * xc, q3 = p11b * xc;
            a0.u[0] = cvtpk(q0[0], q0[1]); a0.u[1] = cvtpk(q0[2], q0[3]);
            a0.u[2] = cvtpk(q1[0], q1[1]); a0.u[3] = cvtpk(q1[2], q1[3]);
            a1.u[0] = cvtpk(q2[0], q2[1]); a1.u[1] = cvtpk(q2[2], q2[3]);
            a1.u[2] = cvtpk(q3[0], q3[1]); a1.u[3] = cvtpk(q3[2], q3[3]);
            acc[1][0] = __builtin_amdgcn_mfma_f32_16x16x32_bf16(a0.s, b00, acc[1][0], 0, 0, 0);
            acc[1][0] = __builtin_amdgcn_mfma_f32_16x16x32_bf16(a1.s, b01, acc[1][0], 0, 0, 0);
            acc[1][1] = __builtin_amdgcn_mfma_f32_16x16x32_bf16(a0.s, b10, acc[1][1], 0, 0, 0);
            acc[1][1] = __builtin_amdgcn_mfma_f32_16x16x32_bf16(a1.s, b11, acc[1][1], 0, 0, 0);
        }

        __syncthreads();                // full drain: next chunk resident, reads done
    }
#undef STAGE_CHUNK

    // epilogue: C/D layout col = lane&15 (n), row = (lane>>4)*4 + j
    float* gp = g + (size_t)split * ((size_t)S_DIM * 64);
    int col0 = lane & 15;
    #pragma unroll
    for (int rg = 0; rg < 2; ++rg) {
        int crow = m0 + rgbase + (rg << 4) + ((lane >> 4) << 2);
        #pragma unroll
        for (int q = 0; q < 2; ++q) {
            int ncol = ((ntb + q) << 4) + col0;
            #pragma unroll
            for (int j = 0; j < 4; ++j)
                gp[((size_t)(crow + j) << 6) + ncol] = acc[rg][q][j];
        }
    }
}

// ---------------------------------------------------------------------------
// K4: out[s,n] = (sum_l w_l * G[s+l-7, n]) * rsq[s] + b[n],  G = sum of 4 partials
// ---------------------------------------------------------------------------
__global__ __launch_bounds__(256) void k_final(const float* __restrict__ g,
                                               const float* __restrict__ rsq,
                                               const float* __restrict__ w,
                                               const float* __restrict__ conv_b,
                                               float* __restrict__ out) {
    int lane = threadIdx.x & 63, wv = threadIdx.x >> 6;
    int wid = blockIdx.x * 4 + wv;           // 0..1023
    int t0 = wid << 4;
    int bt0 = t0 & (T_DIM - 1);
    const size_t SP = (size_t)S_DIM * 64;
    float r[30];
    #pragma unroll
    for (int i = 0; i < 30; ++i) {
        int tr = bt0 - 7 + i;
        r[i] = 0.f;
        if (0 <= tr && tr < T_DIM) {
            const float* p = g + (((size_t)(t0 - 7 + i)) << 6) + lane;
            r[i] = (p[0] + p[SP]) + (p[2 * SP] + p[3 * SP]);
        }
    }
    float bn = conv_b[lane];
    #pragma unroll
    for (int i = 0; i < 16; ++i) {
        float acc = 0.f;
        #pragma unroll
        for (int l = 0; l < 15; ++l) acc += w[l] * r[i + l];
        out[(((size_t)(t0 + i)) << 6) + lane] = acc * rsq[t0 + i] + bn;
    }
}

// ---------------------------------------------------------------------------
extern "C" void kernel_launch(void* const* d_in, const int* in_sizes, int n_in,
                              void* d_out, int out_size, void* d_ws, size_t ws_size,
                              hipStream_t stream) {
    const float* x      = (const float*)d_in[0];
    const float* w      = (const float*)d_in[1];
    const float* conv_w = (const float*)d_in[2];
    const float* conv_b = (const float*)d_in[3];
    float* out = (float*)d_out;

    char* ws = (char*)d_ws;
    unsigned short* wfrag = (unsigned short*)ws;                     //    524,288 B
    float* g              = (float*)(ws + 524288);                   // 16,777,216 B (4 K-split partials)
    float* P              = (float*)(ws + 524288 + 16777216);        //  1,048,576 B
    float* rsq            = P + (size_t)15 * S_DIM;

    hipLaunchKernelGGL(k_convert, dim3(64),   dim3(256), 0, stream, conv_w, wfrag);
    hipLaunchKernelGGL(k_dotsP,   dim3(256),  dim3(256), 0, stream, x, w, P);
    hipLaunchKernelGGL(k_gemm,    dim3(1024), dim3(256), 0, stream, x, wfrag, g);
    hipLaunchKernelGGL(k_rsq,     dim3(64),   dim3(256), 0, stream, P, w, rsq);
    hipLaunchKernelGGL(k_final,   dim3(256),  dim3(256), 0, stream, g, rsq, w, conv_b, out);
}

// Round 13
// 52.230 us; speedup vs baseline: 1.1570x; 1.1570x over previous
//
#include <hip/hip_runtime.h>
#include <stdint.h>

#define T_DIM 4096
#define S_DIM 16384          // 4 batches x 4096
#define EPSF 1e-12f

typedef __attribute__((ext_vector_type(8))) short   short8v;
typedef __attribute__((ext_vector_type(4))) float   float4v;
typedef __attribute__((ext_vector_type(4))) uint32_t uint4v;

__device__ __forceinline__ unsigned short f2bf_rne(float f) {
    uint32_t u = __builtin_bit_cast(uint32_t, f);
    return (unsigned short)((u + 0x7fffu + ((u >> 16) & 1u)) >> 16);
}
__device__ __forceinline__ uint32_t cvtpk(float lo, float hi) {
    uint32_t r;
    asm("v_cvt_pk_bf16_f32 %0, %1, %2" : "=v"(r) : "v"(lo), "v"(hi));
    return r;
}

#define GLOAD_LDS16(gsrc, ldst)                                                     \
    __builtin_amdgcn_global_load_lds(                                               \
        (const __attribute__((address_space(1))) void*)(gsrc),                      \
        (__attribute__((address_space(3))) void*)(ldst), 16, 0, 0)

// ---------------------------------------------------------------------------
// K0: conv_w [k=4096][n=64] f32 -> bf16 fragment stream wfrag[cc][nt][h][ln]x16B
//     granule (cc,nt,h,ln) holds W[cc*64 + h*32 + (ln>>4)*8 + j][nt*16+(ln&15)]
// ---------------------------------------------------------------------------
__global__ __launch_bounds__(256) void k_convert(const float* __restrict__ conv_w,
                                                 unsigned short* __restrict__ wfrag) {
    __shared__ unsigned short lb[64][65];
    int tid = threadIdx.x;
    int cc  = blockIdx.x;                       // 0..63
    for (int i = tid; i < 4096; i += 256) {     // coalesced read of 16KB slab
        lb[i >> 6][i & 63] = f2bf_rne(conv_w[((size_t)cc << 12) + i]);
    }
    __syncthreads();
    for (int gi = tid; gi < 512; gi += 256) {
        int nt = gi >> 7, h = (gi >> 6) & 1, ln = gi & 63;
        int n  = (nt << 4) + (ln & 15);
        int kb = (h << 5) + ((ln >> 4) << 3);
        uint4v u;
        #pragma unroll
        for (int q = 0; q < 4; ++q)
            u[q] = (uint32_t)lb[kb + 2 * q][n] | ((uint32_t)lb[kb + 2 * q + 1][n] << 16);
        *(uint4v*)(wfrag + ((size_t)cc << 12) + (gi << 3)) = u;
    }
}

// ---------------------------------------------------------------------------
// K1: dots + norm partials.  Block = 64 positions (lane = position).
// ---------------------------------------------------------------------------
__global__ __launch_bounds__(256) void k_dotsP(const float* __restrict__ x,
                                               const float* __restrict__ w,
                                               float* __restrict__ P) {
    __shared__ float xt[78 * 65];       // pitch 65, rows s0..s0+77
    __shared__ float pd[4][64][17];
    __shared__ float dsq[64][17];
    int tid = threadIdx.x, lane = tid & 63, wv = tid >> 6;
    int s0 = blockIdx.x << 6;
    int bt0 = s0 & (T_DIM - 1);
    for (int i = tid; i < 78 * 16; i += 256) {
        int r = i >> 4, c4 = (i & 15) << 2;
        float4v v = {0.f, 0.f, 0.f, 0.f};
        if (bt0 + r < T_DIM) v = *(const float4v*)(x + (((size_t)(s0 + r)) << 6) + c4);
        #pragma unroll
        for (int q = 0; q < 4; ++q) xt[r * 65 + c4 + q] = v[q];
    }
    __syncthreads();
    float acc[15];
    #pragma unroll
    for (int j = 0; j < 15; ++j) acc[j] = 0.f;
    int c0 = wv << 4;
    for (int c = c0; c < c0 + 16; ++c) {
        const float* base = &xt[lane * 65 + c];
        float xl = base[0];
        #pragma unroll
        for (int j = 0; j < 15; ++j) acc[j] += xl * base[j * 65];
    }
    #pragma unroll
    for (int j = 0; j < 15; ++j) pd[wv][lane][j] = acc[j];
    __syncthreads();
    for (int i = tid; i < 960; i += 256) {      // i = j*64 + s
        int s = i & 63, j = i >> 6;
        float d = pd[0][s][j] + pd[1][s][j] + pd[2][s][j] + pd[3][s][j];
        dsq[s][j] = d * d;
    }
    __syncthreads();
    for (int i = tid; i < 960; i += 256) {      // i = l*64 + s  (coalesced P writes)
        int s = i & 63, l = i >> 6;
        float sum = w[l] * dsq[s][0];
        for (int j = 1; j <= 14 - l; ++j) sum += 2.f * w[l + j] * dsq[s][j];
        P[(size_t)l * S_DIM + s0 + s] = sum;
    }
}

// ---------------------------------------------------------------------------
// K2: rsq[s] = rsqrt(max(sum_l w_l * P[l][s+l-7], eps))
// ---------------------------------------------------------------------------
__global__ __launch_bounds__(256) void k_rsq(const float* __restrict__ P,
                                             const float* __restrict__ w,
                                             float* __restrict__ rsq) {
    int s = blockIdx.x * 256 + threadIdx.x;
    int t = s & (T_DIM - 1);
    float sum = 0.f;
    #pragma unroll
    for (int l = 0; l < 15; ++l) {
        int tp = t + l - 7;
        if (0 <= tp && tp < T_DIM) sum += w[l] * P[(size_t)l * S_DIM + s + l - 7];
    }
    rsq[s] = rsqrtf(fmaxf(sum, EPSF));
}

// ---------------------------------------------------------------------------
// K3: GEMM g_part[split][s][n] (M=16384, K=4096, N=64), F on the fly.
// MEASURED CHAMPION (R8: 51.95us total, gemm ~7.5us). Stage the 8KB chunk
// once per block into LDS, T3-minimal 2-phase schedule (stage next chunk
// issued BEFORE compute; one full-drain __syncthreads per iter). Broadcast
// granule reads (all 4 waves read identical addresses) measured FASTER than
// every per-wave-distinct remap tried (R9-R12 all regressed 3-13us).
// unroll 2 only (full unroll miscompiles — R5 bisection). split=4, BM=64,
// 1024 blocks = 4 blocks/CU (required occupancy — R9/R11 showed 1-2
// blocks/CU loses more to barrier stalls than any traffic saving gains).
// absmax canary: exactly 4.882812e-4.
// ---------------------------------------------------------------------------
__global__ __launch_bounds__(256) void k_gemm(const float* __restrict__ x,
                                              const unsigned short* __restrict__ wfrag,
                                              float* __restrict__ g) {
    __shared__ alignas(16) unsigned short wbuf[2][4096];   // 2 x 8KB chunk
    int tid = threadIdx.x, lane = tid & 63, wv = tid >> 6;
    int split = blockIdx.x & 3;
    int m0 = (blockIdx.x >> 2) << 6;
    int c0 = split << 4;

    int prow = (wv << 4) + (lane & 15);
    int kgrp = (lane >> 4) << 3;
    const float* xr = x + (((size_t)(m0 + prow)) << 6);
    // A-operand d-half registers (fixed across the K loop)
    float4v p00 = *(const float4v*)(xr + kgrp);
    float4v p01 = *(const float4v*)(xr + kgrp + 4);
    float4v p10 = *(const float4v*)(xr + 32 + kgrp);
    float4v p11 = *(const float4v*)(xr + 36 + kgrp);

    const char* wsb = (const char*)wfrag;
    // stage = 8KB chunk: 2 rounds of 256 lanes x 16B; LDS dest wave-uniform
#define STAGE_CHUNK(bi, c) do {                                                   \
        GLOAD_LDS16(wsb + ((size_t)(c) << 13) + (tid << 4),                       \
                    (char*)&wbuf[bi][0] + (wv << 10));                            \
        GLOAD_LDS16(wsb + ((size_t)(c) << 13) + 4096 + (tid << 4),                \
                    (char*)&wbuf[bi][0] + 4096 + (wv << 10));                     \
    } while (0)

    float4v acc[4];
    #pragma unroll
    for (int nt = 0; nt < 4; ++nt)
        #pragma unroll
        for (int j = 0; j < 4; ++j) acc[nt][j] = 0.f;

    const short8v* fb0 = (const short8v*)&wbuf[0][0];
    const short8v* fb1 = (const short8v*)&wbuf[1][0];

    STAGE_CHUNK(0, c0);
    __syncthreads();                    // chunk 0 resident

    #pragma unroll 2
    for (int ci = 0; ci < 16; ++ci) {
        if (ci < 15) STAGE_CHUNK((ci + 1) & 1, c0 + ci + 1);   // overlaps compute

        const short8v* fb = (ci & 1) ? fb1 : fb0;
        short8v b0 = fb[lane];
        short8v b1 = fb[64 + lane];
        short8v b2 = fb[128 + lane];
        short8v b3 = fb[192 + lane];
        short8v b4 = fb[256 + lane];
        short8v b5 = fb[320 + lane];
        short8v b6 = fb[384 + lane];
        short8v b7 = fb[448 + lane];

        float xc = xr[c0 + ci];         // scalar L1-hit load
        union { uint32_t u[4]; short8v s; } a0, a1;
        float4v q0 = p00 * xc, q1 = p01 * xc, q2 = p10 * xc, q3 = p11 * xc;
        a0.u[0] = cvtpk(q0[0], q0[1]); a0.u[1] = cvtpk(q0[2], q0[3]);
        a0.u[2] = cvtpk(q1[0], q1[1]); a0.u[3] = cvtpk(q1[2], q1[3]);
        a1.u[0] = cvtpk(q2[0], q2[1]); a1.u[1] = cvtpk(q2[2], q2[3]);
        a1.u[2] = cvtpk(q3[0], q3[1]); a1.u[3] = cvtpk(q3[2], q3[3]);

        acc[0] = __builtin_amdgcn_mfma_f32_16x16x32_bf16(a0.s, b0, acc[0], 0, 0, 0);
        acc[0] = __builtin_amdgcn_mfma_f32_16x16x32_bf16(a1.s, b1, acc[0], 0, 0, 0);
        acc[1] = __builtin_amdgcn_mfma_f32_16x16x32_bf16(a0.s, b2, acc[1], 0, 0, 0);
        acc[1] = __builtin_amdgcn_mfma_f32_16x16x32_bf16(a1.s, b3, acc[1], 0, 0, 0);
        acc[2] = __builtin_amdgcn_mfma_f32_16x16x32_bf16(a0.s, b4, acc[2], 0, 0, 0);
        acc[2] = __builtin_amdgcn_mfma_f32_16x16x32_bf16(a1.s, b5, acc[2], 0, 0, 0);
        acc[3] = __builtin_amdgcn_mfma_f32_16x16x32_bf16(a0.s, b6, acc[3], 0, 0, 0);
        acc[3] = __builtin_amdgcn_mfma_f32_16x16x32_bf16(a1.s, b7, acc[3], 0, 0, 0);

        __syncthreads();                // full drain: next chunk resident, reads done
    }
#undef STAGE_CHUNK

    // epilogue: C/D layout col = lane&15 (n), row = (lane>>4)*4 + j
    float* gp = g + (size_t)split * ((size_t)S_DIM * 64);
    int crow0 = m0 + (wv << 4) + ((lane >> 4) << 2);
    int col0 = lane & 15;
    #pragma unroll
    for (int nt = 0; nt < 4; ++nt)
        #pragma unroll
        for (int j = 0; j < 4; ++j)
            gp[((size_t)(crow0 + j) << 6) + (nt << 4) + col0] = acc[nt][j];
}

// ---------------------------------------------------------------------------
// K4: out[s,n] = (sum_l w_l * G[s+l-7, n]) * rsq[s] + b[n],  G = sum of 4 partials
// ---------------------------------------------------------------------------
__global__ __launch_bounds__(256) void k_final(const float* __restrict__ g,
                                               const float* __restrict__ rsq,
                                               const float* __restrict__ w,
                                               const float* __restrict__ conv_b,
                                               float* __restrict__ out) {
    int lane = threadIdx.x & 63, wv = threadIdx.x >> 6;
    int wid = blockIdx.x * 4 + wv;           // 0..1023
    int t0 = wid << 4;
    int bt0 = t0 & (T_DIM - 1);
    const size_t SP = (size_t)S_DIM * 64;
    float r[30];
    #pragma unroll
    for (int i = 0; i < 30; ++i) {
        int tr = bt0 - 7 + i;
        r[i] = 0.f;
        if (0 <= tr && tr < T_DIM) {
            const float* p = g + (((size_t)(t0 - 7 + i)) << 6) + lane;
            r[i] = (p[0] + p[SP]) + (p[2 * SP] + p[3 * SP]);
        }
    }
    float bn = conv_b[lane];
    #pragma unroll
    for (int i = 0; i < 16; ++i) {
        float acc = 0.f;
        #pragma unroll
        for (int l = 0; l < 15; ++l) acc += w[l] * r[i + l];
        out[(((size_t)(t0 + i)) << 6) + lane] = acc * rsq[t0 + i] + bn;
    }
}

// ---------------------------------------------------------------------------
extern "C" void kernel_launch(void* const* d_in, const int* in_sizes, int n_in,
                              void* d_out, int out_size, void* d_ws, size_t ws_size,
                              hipStream_t stream) {
    const float* x      = (const float*)d_in[0];
    const float* w      = (const float*)d_in[1];
    const float* conv_w = (const float*)d_in[2];
    const float* conv_b = (const float*)d_in[3];
    float* out = (float*)d_out;

    char* ws = (char*)d_ws;
    unsigned short* wfrag = (unsigned short*)ws;                     //    524,288 B
    float* g              = (float*)(ws + 524288);                   // 16,777,216 B (4 K-split partials)
    float* P              = (float*)(ws + 524288 + 16777216);        //  1,048,576 B
    float* rsq            = P + (size_t)15 * S_DIM;

    hipLaunchKernelGGL(k_convert, dim3(64),   dim3(256), 0, stream, conv_w, wfrag);
    hipLaunchKernelGGL(k_dotsP,   dim3(256),  dim3(256), 0, stream, x, w, P);
    hipLaunchKernelGGL(k_gemm,    dim3(1024), dim3(256), 0, stream, x, wfrag, g);
    hipLaunchKernelGGL(k_rsq,     dim3(64),   dim3(256), 0, stream, P, w, rsq);
    hipLaunchKernelGGL(k_final,   dim3(256),  dim3(256), 0, stream, g, rsq, w, conv_b, out);
}